// Round 10
// baseline (6970.013 us; speedup 1.0000x reference)
//
#include <hip/hip_runtime.h>
#include <hip/hip_bf16.h>

#define NB 256   // batch
#define NS 512   // seq len
#define NV 4     // vocab
#define NH 512   // encoder hidden
#define CH 16    // steps per chunk
#define NCH 32   // chunks

typedef __bf16 bf16x8 __attribute__((ext_vector_type(8)));
typedef float  f32x4  __attribute__((ext_vector_type(4)));

// ---- workspace byte offsets ----
// flags : 4 KB   (F[g*16]=A prog, F[256+g*16]=B prog, F[512+g*32+c]=zdone)
// h1ring: [g][parity][t][ks16][slot64][16B]  8 MB
// zring : [g][parity][t][gt32][l64][16B]     16 MB (f32x4)
// enc   : [B][H] f32                         512 KB
// frag  : 3 x 512KB bf16 B-frags (Whh0, Whh1, Wih1)
#define H1RING_OFF  8192
#define ZRING_OFF   (H1RING_OFF + (8u << 20))
#define ENC_OFF     (ZRING_OFF + (16u << 20))
#define CM_OFF      (ENC_OFF + NB*NH*4)
#define RS_OFF      (CM_OFF + 2048)
#define FRAG_OFF    (RS_OFF + 2048)

__device__ __forceinline__ float fast_tanh(float x) {
    x = fminf(12.0f, fmaxf(-12.0f, x));
    float e = __expf(2.0f * x);
    return (e - 1.0f) / (e + 1.0f);
}

__device__ __forceinline__ int aload(int* p) {
    return __hip_atomic_load(p, __ATOMIC_ACQUIRE, __HIP_MEMORY_SCOPE_AGENT);
}

// physical byte offset of logical A-frag slot (bank-conflict swizzle)
__device__ __forceinline__ int swzb(int slot) {
    return (slot << 4) ^ (((slot >> 2) & 1) << 5);
}

// MFMA with the B operand forced into the AGPR file ("a" constraint).
// r9 finding: the allocator pins arch VGPRs at 128 regardless of
// launch_bounds/waves_per_eu/pin -> WR[12][4] (192 regs) can never be
// arch-VGPR-resident.  gfx950 MFMA reads A/B from VGPR or AGPR, and the
// AGPR half of the unified file (256/wave) is NOT governed by that cap,
// so weights parked there stay resident with zero per-step reload.
__device__ __forceinline__ void mfma_aw(f32x4& c, const bf16x8 a, const bf16x8 b_ag) {
    asm("v_mfma_f32_16x16x32_bf16 %0, %1, %2, %0"
        : "+v"(c) : "v"(a), "a"(b_ag));
}

// ---------------------------------------------------------------------------
// One-shot: re-lay weight matrices as bf16 MFMA B-fragments.
// frag[mt] layout: ((ks*32 + gt)*64 + l)*16 bytes, gt = n-tile 0..31.
// ---------------------------------------------------------------------------
__global__ void prep_kernel(const float* __restrict__ W0, const float* __restrict__ W1,
                            const float* __restrict__ WG, char* __restrict__ ws)
{
    const int mt = blockIdx.x >> 5;     // 0=Whh0, 1=Whh1, 2=Wih1
    const int gt = blockIdx.x & 31;
    const float* src = (mt == 0) ? W0 : (mt == 1) ? W1 : WG;
    char* dst = ws + FRAG_OFF + (size_t)mt * (1u << 19);
    const int tid = threadIdx.x;
#pragma unroll
    for (int s = 0; s < 4; ++s) {
        const int e  = tid + s * 256;    // 0..1023
        const int ks = e >> 6, ll = e & 63;
        const int col = gt * 16 + (ll & 15);
        const float* p = src + (size_t)col * NH + ks * 32 + ((ll >> 4) << 3);
        bf16x8 v;
#pragma unroll
        for (int j = 0; j < 8; ++j) v[j] = (__bf16)p[j];
        *(bf16x8*)(dst + ((size_t)(ks * 32 + gt) * 64 + ll) * 16) = v;
    }
}

// ---------------------------------------------------------------------------
// Persistent pipeline: 48 WGs x 512 threads, 1 block/CU (LDS-limited).
// role A (blk 0-15):  h1 chain, weights AGPR-resident, publishes h1 chunks.
// role B (blk 16-31): h2 chain, consumes z chunks, emits pre-tanh encoded.
// role G (blk 32-47): z = h1 @ Wih1^T + b, weights AGPR-resident.
// ---------------------------------------------------------------------------
extern "C" __global__ __launch_bounds__(512, 1)
void persist_kernel(const float* __restrict__ x,
                    const float* __restrict__ eWih0,
                    const float* __restrict__ ebih0, const float* __restrict__ ebhh0,
                    const float* __restrict__ ebih1, const float* __restrict__ ebhh1,
                    char* __restrict__ ws)
{
    extern __shared__ char lds[];
    int*   F      = (int*)ws;
    char*  h1ring = ws + H1RING_OFF;
    char*  zring  = ws + ZRING_OFF;
    float* enc    = (float*)(ws + ENC_OFF);
    const char* fragA = ws + FRAG_OFF;                 // Whh0
    const char* fragB = ws + FRAG_OFF + (1u << 19);    // Whh1
    const char* fragG = ws + FRAG_OFF + (2u << 19);    // Wih1

    const int blk  = blockIdx.x;
    const int role = blk >> 4;     // 0=A, 1=B, 2=G
    const int g    = blk & 15;
    const int tid  = threadIdx.x;
    const int wq   = tid >> 6;     // wave 0..7
    const int l    = tid & 63;
    const int lm   = l & 15;
    const int q    = l >> 4;
    const int rdoff = (l << 4) ^ (((l >> 2) & 1) << 5);  // swizzled A-frag read

    if (role <= 1) {
        // ================= chain roles (A: layer-0, B: layer-1) =================
        const bool isA = (role == 0);
        const char* frag = isA ? fragA : fragB;

        char* HS = lds;            // [0,32768) h-state double buffer
        char* WL = lds + 32768;    // [32768,163840) K-steps 12..15 B-frags

        // zero initial state (buffer 0)
        {
            bf16x8 z8;
#pragma unroll
            for (int j = 0; j < 8; ++j) z8[j] = (__bf16)0.f;
            for (int o = tid; o < 1024; o += 512) *(bf16x8*)(HS + o * 16) = z8;
        }

        // ---- weights: 12 K-steps -> AGPRs (192), 4 K-steps -> LDS ----
        bf16x8 WR[12][4];
#pragma unroll
        for (int ks = 0; ks < 12; ++ks)
#pragma unroll
            for (int n = 0; n < 4; ++n)
                WR[ks][n] = *(const bf16x8*)(frag + ((size_t)(ks * 32 + wq * 4 + n) * 64 + l) * 16);
#pragma unroll
        for (int ks = 12; ks < 16; ++ks)
#pragma unroll
            for (int n = 0; n < 4; ++n) {
                const bf16x8 v = *(const bf16x8*)(frag + ((size_t)(ks * 32 + wq * 4 + n) * 64 + l) * 16);
                *(bf16x8*)(WL + (((ks - 12) * 32 + wq * 4 + n) * 64 + l) * 16) = v;
            }

        bf16x8 EB[4];
        float  bias[4];
#pragma unroll
        for (int n = 0; n < 4; ++n) {
            const int col = wq * 64 + n * 16 + lm;
#pragma unroll
            for (int j = 0; j < 8; ++j) EB[n][j] = (__bf16)0.f;
            if (isA) {
                if (q == 0) {
                    const float4 w0 = *(const float4*)(eWih0 + (size_t)col * NV);
                    EB[n][0] = (__bf16)w0.x; EB[n][1] = (__bf16)w0.y;
                    EB[n][2] = (__bf16)w0.z; EB[n][3] = (__bf16)w0.w;
                }
                bias[n] = ebih0[col] + ebhh0[col];
            } else {
                bias[n] = 0.f;  // z already contains layer-1 biases
            }
        }
        __syncthreads();

#pragma unroll 1
        for (int c = 0; c < NCH; ++c) {
            // ---- chunk-entry sync ----
            if (isA) {
                if (c >= 2) {   // backpressure: G consumed h1 chunk c-2 (same parity)
                    if (tid == 0)
                        while (aload(&F[512 + g * 32 + (c - 2)]) < 1)
                            __builtin_amdgcn_s_sleep(8);
                    __syncthreads();
                }
            } else {
                if (tid == 0)
                    while (aload(&F[512 + g * 32 + c]) < 1)
                        __builtin_amdgcn_s_sleep(8);
                __syncthreads();
                __builtin_amdgcn_fence(__ATOMIC_ACQUIRE, "agent");
            }

            char* rsl = h1ring + (size_t)((g * 2 + (c & 1)) * CH) * 16384;  // A writes
            char* zsl = zring  + (size_t)((g * 2 + (c & 1)) * CH) * 32768;  // B reads

            f32x4 zn[4];
            if (!isA) {
#pragma unroll
                for (int n = 0; n < 4; ++n)
                    zn[n] = *(const f32x4*)(zsl + ((wq * 4 + n) * 64 + l) * 16);
            }

#pragma unroll 1
            for (int t = 0; t < CH; ++t) {
                const int i  = c * CH + t;
                const int rb = t & 1;
                const char* hsr = HS + rb * 16384;
                char*       hsw = HS + (rb ^ 1) * 16384;

                f32x4 acc[4];
                bf16x8 xa;
                if (isA) {
#pragma unroll
                    for (int n = 0; n < 4; ++n)
                        acc[n] = (f32x4){bias[n], bias[n], bias[n], bias[n]};
                    const float4 xv = *(const float4*)(x + ((size_t)(g * 16 + lm) * NS + i) * NV);
#pragma unroll
                    for (int j = 0; j < 8; ++j) xa[j] = (__bf16)0.f;
                    if (q == 0) {
                        xa[0] = (__bf16)xv.x; xa[1] = (__bf16)xv.y;
                        xa[2] = (__bf16)xv.z; xa[3] = (__bf16)xv.w;
                    }
                } else {
#pragma unroll
                    for (int n = 0; n < 4; ++n) acc[n] = zn[n];
                    if (t + 1 < CH) {
#pragma unroll
                        for (int n = 0; n < 4; ++n)
                            zn[n] = *(const f32x4*)(zsl + (size_t)(t + 1) * 32768 +
                                                    ((wq * 4 + n) * 64 + l) * 16);
                    }
                }

                // ---- K-steps (0-11: AGPR-resident weights via asm MFMA) ----
#pragma unroll
                for (int ks = 0; ks < 12; ++ks) {
                    const bf16x8 af = *(const bf16x8*)(hsr + ks * 1024 + rdoff);
#pragma unroll
                    for (int n = 0; n < 4; ++n)
                        mfma_aw(acc[n], af, WR[ks][n]);
                }
#pragma unroll
                for (int ks = 12; ks < 16; ++ks) {
                    const bf16x8 af = *(const bf16x8*)(hsr + ks * 1024 + rdoff);
#pragma unroll
                    for (int n = 0; n < 4; ++n) {
                        const bf16x8 bfr = *(const bf16x8*)(WL + (((ks - 12) * 32 + wq * 4 + n) * 64 + l) * 16);
                        acc[n] = __builtin_amdgcn_mfma_f32_16x16x32_bf16(af, bfr, acc[n], 0, 0, 0);
                    }
                }
                if (isA) {  // x @ Wih0^T extension K-step
#pragma unroll
                    for (int n = 0; n < 4; ++n)
                        mfma_aw(acc[n], xa, EB[n]);
                }

                // ---- epilogue ----
                if (!isA && i == NS - 1) {
                    // encoded = PRE-tanh (arctanh(tanh(s)) == s)
#pragma unroll
                    for (int n = 0; n < 4; ++n) {
                        const int col = wq * 64 + n * 16 + lm;
#pragma unroll
                        for (int jr = 0; jr < 4; ++jr)
                            enc[(size_t)(g * 16 + q * 4 + jr) * NH + col] = acc[n][jr];
                    }
                } else {
#pragma unroll
                    for (int n = 0; n < 4; ++n) {
                        const int col = wq * 64 + n * 16 + lm;
                        const int ks  = col >> 5;
                        const int cq  = (col >> 3) & 3;
                        const int bo  = (col & 7) * 2;
#pragma unroll
                        for (int jr = 0; jr < 4; ++jr) {
                            const float th = fast_tanh(acc[n][jr]);
                            const int slot = (q * 4 + jr) | (cq << 4);
                            *(__bf16*)(hsw + ks * 1024 + swzb(slot) + bo) = (__bf16)th;
                        }
                    }
                }
                __syncthreads();  // hsw complete for all waves

                if (isA) {
                    // copy new h1 (LDS swizzled) -> h1ring (global, logical-linear)
                    char* rdst = rsl + (size_t)t * 16384;
#pragma unroll
                    for (int e = tid; e < 1024; e += 512) {
                        const int ks = e >> 6, slot = e & 63;
                        const bf16x8 v = *(const bf16x8*)(hsw + ks * 1024 + swzb(slot));
                        *(bf16x8*)(rdst + ks * 1024 + slot * 16) = v;
                    }
                }
            }

            // ---- chunk-exit publish ----
            __syncthreads();
            if (tid == 0) {
                if (isA)
                    __hip_atomic_store(&F[g * 16], c + 1, __ATOMIC_RELEASE, __HIP_MEMORY_SCOPE_AGENT);
                else
                    __hip_atomic_store(&F[256 + g * 16], c + 1, __ATOMIC_RELEASE, __HIP_MEMORY_SCOPE_AGENT);
            }
        }
    } else {
        // ================= G role: z[c] = h1[c] @ Wih1^T + bias =================
        char* HB = lds;            // [0,32768) h1 t-slab double buffer
        char* WL = lds + 32768;

        bf16x8 WR[12][4];
#pragma unroll
        for (int ks = 0; ks < 12; ++ks)
#pragma unroll
            for (int n = 0; n < 4; ++n)
                WR[ks][n] = *(const bf16x8*)(fragG + ((size_t)(ks * 32 + wq * 4 + n) * 64 + l) * 16);
#pragma unroll
        for (int ks = 12; ks < 16; ++ks)
#pragma unroll
            for (int n = 0; n < 4; ++n) {
                const bf16x8 v = *(const bf16x8*)(fragG + ((size_t)(ks * 32 + wq * 4 + n) * 64 + l) * 16);
                *(bf16x8*)(WL + (((ks - 12) * 32 + wq * 4 + n) * 64 + l) * 16) = v;
            }
        float bv[4];
#pragma unroll
        for (int n = 0; n < 4; ++n) {
            const int col = wq * 64 + n * 16 + lm;
            bv[n] = ebih1[col] + ebhh1[col];
        }
        __syncthreads();

#pragma unroll 1
        for (int c = 0; c < NCH; ++c) {
            if (tid == 0) {
                while (aload(&F[g * 16]) < c + 1) __builtin_amdgcn_s_sleep(8);
                if (c >= 2)
                    while (aload(&F[256 + g * 16]) < c - 1) __builtin_amdgcn_s_sleep(8);
            }
            __syncthreads();
            __builtin_amdgcn_fence(__ATOMIC_ACQUIRE, "agent");

            const char* rsl = h1ring + (size_t)((g * 2 + (c & 1)) * CH) * 16384;
            char*       zsl = zring  + (size_t)((g * 2 + (c & 1)) * CH) * 32768;

            // stage t=0 (32 B/thread, coalesced)
            {
                const char* s = rsl + tid * 32;
                const f32x4 a0 = *(const f32x4*)(s);
                const f32x4 a1 = *(const f32x4*)(s + 16);
                *(f32x4*)(HB + tid * 32)      = a0;
                *(f32x4*)(HB + tid * 32 + 16) = a1;
            }
            __syncthreads();

#pragma unroll 1
            for (int t = 0; t < CH; ++t) {
                const char* bufr = HB + (t & 1) * 16384;
                char*       bufw = HB + ((t + 1) & 1) * 16384;
                f32x4 p0, p1;
                const bool pf = (t + 1 < CH);
                if (pf) {
                    const char* s = rsl + (size_t)(t + 1) * 16384 + tid * 32;
                    p0 = *(const f32x4*)(s);
                    p1 = *(const f32x4*)(s + 16);
                }

                f32x4 acc[4];
#pragma unroll
                for (int n = 0; n < 4; ++n)
                    acc[n] = (f32x4){bv[n], bv[n], bv[n], bv[n]};
#pragma unroll
                for (int ks = 0; ks < 12; ++ks) {
                    const bf16x8 af = *(const bf16x8*)(bufr + ks * 1024 + l * 16);
#pragma unroll
                    for (int n = 0; n < 4; ++n)
                        mfma_aw(acc[n], af, WR[ks][n]);
                }
#pragma unroll
                for (int ks = 12; ks < 16; ++ks) {
                    const bf16x8 af = *(const bf16x8*)(bufr + ks * 1024 + l * 16);
#pragma unroll
                    for (int n = 0; n < 4; ++n) {
                        const bf16x8 bfr = *(const bf16x8*)(WL + (((ks - 12) * 32 + wq * 4 + n) * 64 + l) * 16);
                        acc[n] = __builtin_amdgcn_mfma_f32_16x16x32_bf16(af, bfr, acc[n], 0, 0, 0);
                    }
                }
#pragma unroll
                for (int n = 0; n < 4; ++n)
                    *(f32x4*)(zsl + (size_t)t * 32768 + ((wq * 4 + n) * 64 + l) * 16) = acc[n];

                __syncthreads();            // everyone done reading bufw's old data
                if (pf) {
                    *(f32x4*)(bufw + tid * 32)      = p0;
                    *(f32x4*)(bufw + tid * 32 + 16) = p1;
                }
                __syncthreads();            // staged slab visible
            }

            __syncthreads();
            if (tid == 0)
                __hip_atomic_store(&F[512 + g * 32 + c], 1, __ATOMIC_RELEASE, __HIP_MEMORY_SCOPE_AGENT);
        }
    }
}

// ---------------------------------------------------------------------------
// Batch-axis softmax stats per hidden column.
// ---------------------------------------------------------------------------
__global__ void colstats_kernel(const float* __restrict__ encoded,
                                float* __restrict__ colmax,
                                float* __restrict__ rsinv)
{
    const int h = blockIdx.x;
    const int lane = threadIdx.x;  // 64
    float v[4];
#pragma unroll
    for (int r = 0; r < 4; ++r) v[r] = encoded[(size_t)(lane + 64 * r) * NH + h];
    float mx = fmaxf(fmaxf(v[0], v[1]), fmaxf(v[2], v[3]));
#pragma unroll
    for (int s = 1; s < 64; s <<= 1) mx = fmaxf(mx, __shfl_xor(mx, s));
    float sum = 0.f;
#pragma unroll
    for (int r = 0; r < 4; ++r) sum += __expf(v[r] - mx);
#pragma unroll
    for (int s = 1; s < 64; s <<= 1) sum += __shfl_xor(sum, s);
    if (lane == 0) { colmax[h] = mx; rsinv[h] = 1.0f / sum; }
}

// ---------------------------------------------------------------------------
// Decoder: 256 threads, one per batch element; whole 4-dim recurrence in
// registers (no shuffles). Weights broadcast (uniform loads).
// ---------------------------------------------------------------------------
__global__ void decoder_kernel(
    const float* __restrict__ encoded,
    const float* __restrict__ colmax, const float* __restrict__ rsinv,
    const float* __restrict__ dWih0, const float* __restrict__ dWhh0,
    const float* __restrict__ dbih0, const float* __restrict__ dbhh0,
    const float* __restrict__ dWih1, const float* __restrict__ dWhh1,
    const float* __restrict__ dbih1, const float* __restrict__ dbhh1,
    float* __restrict__ out)
{
    const int b = blockIdx.x * 64 + threadIdx.x;

    float W0[16], Wi[16], W1[16];
#pragma unroll
    for (int e = 0; e < 16; ++e) { W0[e] = dWhh0[e]; Wi[e] = dWih1[e]; W1[e] = dWhh1[e]; }

    float c1[4], c2[4];
#pragma unroll
    for (int j = 0; j < 4; ++j) { c1[j] = dbih0[j] + dbhh0[j]; c2[j] = dbih1[j] + dbhh1[j]; }

    // a1[b][j] = bih0[j] + sum_h softmax_batch(enc)[b,h] * Wih0[j,h]
    const float* er = encoded + (size_t)b * NH;
#pragma unroll 1
    for (int h = 0; h < NH; h += 4) {
        const float4 ev = *(const float4*)(er + h);
        const float4 cm = *(const float4*)(colmax + h);
        const float4 rs = *(const float4*)(rsinv + h);
        float p0 = __expf(ev.x - cm.x) * rs.x;
        float p1 = __expf(ev.y - cm.y) * rs.y;
        float p2 = __expf(ev.z - cm.z) * rs.z;
        float p3 = __expf(ev.w - cm.w) * rs.w;
#pragma unroll
        for (int j = 0; j < 4; ++j) {
            const float4 w = *(const float4*)(dWih0 + (size_t)j * NH + h);
            c1[j] += p0 * w.x + p1 * w.y + p2 * w.z + p3 * w.w;
        }
    }

    float h1[4] = {0.f, 0.f, 0.f, 0.f};
    float h2[4] = {0.f, 0.f, 0.f, 0.f};
    float* op = out + (size_t)b * NS * NV;

#pragma unroll 1
    for (int t = 0; t < NS; ++t) {
        float n1[4];
#pragma unroll
        for (int j = 0; j < 4; ++j)
            n1[j] = fast_tanh(c1[j] + W0[j*4+0]*h1[0] + W0[j*4+1]*h1[1]
                                    + W0[j*4+2]*h1[2] + W0[j*4+3]*h1[3]);
        float n2[4];
#pragma unroll
        for (int j = 0; j < 4; ++j)
            n2[j] = fast_tanh(c2[j] + Wi[j*4+0]*n1[0] + Wi[j*4+1]*n1[1]
                                    + Wi[j*4+2]*n1[2] + Wi[j*4+3]*n1[3]
                                    + W1[j*4+0]*h2[0] + W1[j*4+1]*h2[1]
                                    + W1[j*4+2]*h2[2] + W1[j*4+3]*h2[3]);
#pragma unroll
        for (int j = 0; j < 4; ++j) { h1[j] = n1[j]; h2[j] = n2[j]; }
        *(float4*)(op + (size_t)t * NV) = make_float4(n2[0], n2[1], n2[2], n2[3]);
    }
}

extern "C" void kernel_launch(void* const* d_in, const int* in_sizes, int n_in,
                              void* d_out, int out_size, void* d_ws, size_t ws_size,
                              hipStream_t stream)
{
    const float* x     = (const float*)d_in[0];
    const float* eWih0 = (const float*)d_in[1];
    const float* eWhh0 = (const float*)d_in[2];
    const float* ebih0 = (const float*)d_in[3];
    const float* ebhh0 = (const float*)d_in[4];
    const float* eWih1 = (const float*)d_in[5];
    const float* eWhh1 = (const float*)d_in[6];
    const float* ebih1 = (const float*)d_in[7];
    const float* ebhh1 = (const float*)d_in[8];
    const float* dWih0 = (const float*)d_in[9];
    const float* dWhh0 = (const float*)d_in[10];
    const float* dbih0 = (const float*)d_in[11];
    const float* dbhh0 = (const float*)d_in[12];
    const float* dWih1 = (const float*)d_in[13];
    const float* dWhh1 = (const float*)d_in[14];
    const float* dbih1 = (const float*)d_in[15];
    const float* dbhh1 = (const float*)d_in[16];

    char*  ws     = (char*)d_ws;
    float* enc    = (float*)(ws + ENC_OFF);
    float* colmax = (float*)(ws + CM_OFF);
    float* rsinv  = (float*)(ws + RS_OFF);

    hipFuncSetAttribute((const void*)persist_kernel,
                        hipFuncAttributeMaxDynamicSharedMemorySize, 163840);

    // zero flags
    hipMemsetAsync(d_ws, 0, 4096, stream);

    // one-shot weight fragmentation (bf16 B-frag layout)
    prep_kernel<<<96, 256, 0, stream>>>(eWhh0, eWhh1, eWih1, ws);

    // persistent pipelined encoder
    persist_kernel<<<48, 512, 163840, stream>>>(x, eWih0, ebih0, ebhh0,
                                                ebih1, ebhh1, ws);

    colstats_kernel<<<NH, 64, 0, stream>>>(enc, colmax, rsinv);
    decoder_kernel<<<4, 64, 0, stream>>>(enc, colmax, rsinv,
                                         dWih0, dWhh0, dbih0, dbhh0,
                                         dWih1, dWhh1, dbih1, dbhh1,
                                         (float*)d_out);
}

// Round 11
// 2470.855 us; speedup vs baseline: 2.8209x; 2.8209x over previous
//
#include <hip/hip_runtime.h>
#include <hip/hip_bf16.h>

#define NB 256   // batch
#define NS 512   // seq len
#define NV 4     // vocab
#define NH 512   // encoder hidden
#define CH 16    // steps per chunk
#define NCH 32   // chunks

typedef __bf16 bf16x8 __attribute__((ext_vector_type(8)));
typedef float  f32x4  __attribute__((ext_vector_type(4)));

// ---- workspace byte offsets ----
#define H1RING_OFF  8192
#define ZRING_OFF   (H1RING_OFF + (8u << 20))
#define ENC_OFF     (ZRING_OFF + (16u << 20))
#define CM_OFF      (ENC_OFF + NB*NH*4)
#define RS_OFF      (CM_OFF + 2048)
#define FRAG_OFF    (RS_OFF + 2048)

__device__ __forceinline__ float fast_tanh(float x) {
    x = fminf(12.0f, fmaxf(-12.0f, x));
    float e = __expf(2.0f * x);
    return (e - 1.0f) / (e + 1.0f);
}

__device__ __forceinline__ int aload(int* p) {
    return __hip_atomic_load(p, __ATOMIC_ACQUIRE, __HIP_MEMORY_SCOPE_AGENT);
}

// physical byte offset of logical A-frag slot (bank-conflict swizzle)
__device__ __forceinline__ int swzb(int slot) {
    return (slot << 4) ^ (((slot >> 2) & 1) << 5);
}

// ---------------------------------------------------------------------------
// One-shot: re-lay weight matrices as bf16 MFMA B-fragments.
// frag[mt] layout: ((ks*32 + gt)*64 + l)*16 bytes, gt = n-tile 0..31.
// ---------------------------------------------------------------------------
__global__ void prep_kernel(const float* __restrict__ W0, const float* __restrict__ W1,
                            const float* __restrict__ WG, char* __restrict__ ws)
{
    const int mt = blockIdx.x >> 5;     // 0=Whh0, 1=Whh1, 2=Wih1
    const int gt = blockIdx.x & 31;
    const float* src = (mt == 0) ? W0 : (mt == 1) ? W1 : WG;
    char* dst = ws + FRAG_OFF + (size_t)mt * (1u << 19);
    const int tid = threadIdx.x;
#pragma unroll
    for (int s = 0; s < 4; ++s) {
        const int e  = tid + s * 256;    // 0..1023
        const int ks = e >> 6, ll = e & 63;
        const int col = gt * 16 + (ll & 15);
        const float* p = src + (size_t)col * NH + ks * 32 + ((ll >> 4) << 3);
        bf16x8 v;
#pragma unroll
        for (int j = 0; j < 8; ++j) v[j] = (__bf16)p[j];
        *(bf16x8*)(dst + ((size_t)(ks * 32 + gt) * 64 + ll) * 16) = v;
    }
}

// ---------------------------------------------------------------------------
// Persistent pipeline: 48 WGs x 1024 threads (16 waves), 1 block/CU.
// r10 lesson: gfx950's register file is UNIFIED (AGPR==VGPR budget) and the
// HW cap at 16 waves/CU is exactly 128 VGPR/wave.  At 16 waves each wave
// owns 32 cols -> WR[12][2] = 96 weight regs + ~40 working ~= 128: weights
// are register-resident BY CONSTRUCTION (no allocator fight, ~0 hot spills).
// role A (blk 0-15):  h1 chain.   role B (blk 16-31): h2 chain.
// role G (blk 32-47): z = h1 @ Wih1^T + bias.
// ---------------------------------------------------------------------------
extern "C" __global__ __launch_bounds__(1024, 1)
void persist_kernel(const float* __restrict__ x,
                    const float* __restrict__ eWih0,
                    const float* __restrict__ ebih0, const float* __restrict__ ebhh0,
                    const float* __restrict__ ebih1, const float* __restrict__ ebhh1,
                    char* __restrict__ ws)
{
    extern __shared__ char lds[];
    int*   F      = (int*)ws;
    char*  h1ring = ws + H1RING_OFF;
    char*  zring  = ws + ZRING_OFF;
    float* enc    = (float*)(ws + ENC_OFF);
    const char* fragA = ws + FRAG_OFF;                 // Whh0
    const char* fragB = ws + FRAG_OFF + (1u << 19);    // Whh1
    const char* fragG = ws + FRAG_OFF + (2u << 19);    // Wih1

    const int blk  = blockIdx.x;
    const int role = blk >> 4;     // 0=A, 1=B, 2=G
    const int g    = blk & 15;
    const int tid  = threadIdx.x;
    const int wq   = tid >> 6;     // wave 0..15
    const int l    = tid & 63;
    const int lm   = l & 15;
    const int q    = l >> 4;
    const int rdoff = (l << 4) ^ (((l >> 2) & 1) << 5);  // swizzled A-frag read

    if (role <= 1) {
        // ================= chain roles (A: layer-0, B: layer-1) =================
        const bool isA = (role == 0);
        const char* frag = isA ? fragA : fragB;

        char* HS = lds;            // [0,32768) h-state double buffer
        char* WL = lds + 32768;    // [32768,163840) K-steps 12..15 B-frags (all 32 gt)

        // zero initial state (buffer 0; zero both for safety)
        {
            bf16x8 z8;
#pragma unroll
            for (int j = 0; j < 8; ++j) z8[j] = (__bf16)0.f;
            for (int o = tid; o < 2048; o += 1024) *(bf16x8*)(HS + o * 16) = z8;
        }

        // ---- weights: 12 K-steps in VGPR (96 regs/wave), 4 K-steps in LDS ----
        bf16x8 WR[12][2];
#pragma unroll
        for (int ks = 0; ks < 12; ++ks)
#pragma unroll
            for (int n = 0; n < 2; ++n)
                WR[ks][n] = *(const bf16x8*)(frag + ((size_t)(ks * 32 + wq * 2 + n) * 64 + l) * 16);
#pragma unroll
        for (int ks = 12; ks < 16; ++ks)
#pragma unroll
            for (int n = 0; n < 2; ++n) {
                const bf16x8 v = *(const bf16x8*)(frag + ((size_t)(ks * 32 + wq * 2 + n) * 64 + l) * 16);
                *(bf16x8*)(WL + (((ks - 12) * 32 + wq * 2 + n) * 64 + l) * 16) = v;
            }

        bf16x8 EB[2];
        float  bias[2];
#pragma unroll
        for (int n = 0; n < 2; ++n) {
            const int col = (wq * 2 + n) * 16 + lm;
#pragma unroll
            for (int j = 0; j < 8; ++j) EB[n][j] = (__bf16)0.f;
            if (isA) {
                if (q == 0) {
                    const float4 w0 = *(const float4*)(eWih0 + (size_t)col * NV);
                    EB[n][0] = (__bf16)w0.x; EB[n][1] = (__bf16)w0.y;
                    EB[n][2] = (__bf16)w0.z; EB[n][3] = (__bf16)w0.w;
                }
                bias[n] = ebih0[col] + ebhh0[col];
            } else {
                bias[n] = 0.f;  // z already contains layer-1 biases
            }
        }
        __syncthreads();

#pragma unroll 1
        for (int c = 0; c < NCH; ++c) {
            // ---- chunk-entry sync ----
            if (isA) {
                if (c >= 2) {   // backpressure: G consumed h1 chunk c-2 (same parity)
                    if (tid == 0)
                        while (aload(&F[512 + g * 32 + (c - 2)]) < 1)
                            __builtin_amdgcn_s_sleep(2);
                    __syncthreads();
                }
            } else {
                if (tid == 0)
                    while (aload(&F[512 + g * 32 + c]) < 1)
                        __builtin_amdgcn_s_sleep(2);
                __syncthreads();
                __builtin_amdgcn_fence(__ATOMIC_ACQUIRE, "agent");
            }

            char* rsl = h1ring + (size_t)((g * 2 + (c & 1)) * CH) * 16384;  // A writes
            char* zsl = zring  + (size_t)((g * 2 + (c & 1)) * CH) * 32768;  // B reads

#pragma unroll 1
            for (int t = 0; t < CH; ++t) {
                const int i  = c * CH + t;
                const int rb = t & 1;
                const char* hsr = HS + rb * 16384;
                char*       hsw = HS + (rb ^ 1) * 16384;

                f32x4 acc[2];
                bf16x8 xa;
                f32x4 zn0, zn1;
                if (isA) {
#pragma unroll
                    for (int n = 0; n < 2; ++n)
                        acc[n] = (f32x4){bias[n], bias[n], bias[n], bias[n]};
                    const float4 xv = *(const float4*)(x + ((size_t)(g * 16 + lm) * NS + i) * NV);
#pragma unroll
                    for (int j = 0; j < 8; ++j) xa[j] = (__bf16)0.f;
                    if (q == 0) {
                        xa[0] = (__bf16)xv.x; xa[1] = (__bf16)xv.y;
                        xa[2] = (__bf16)xv.z; xa[3] = (__bf16)xv.w;
                    }
                } else {
                    // z loads issued at loop top, consumed in epilogue (latency hidden)
                    zn0 = *(const f32x4*)(zsl + (size_t)t * 32768 + ((wq * 2 + 0) * 64 + l) * 16);
                    zn1 = *(const f32x4*)(zsl + (size_t)t * 32768 + ((wq * 2 + 1) * 64 + l) * 16);
                    acc[0] = (f32x4){0.f, 0.f, 0.f, 0.f};
                    acc[1] = (f32x4){0.f, 0.f, 0.f, 0.f};
                }

                // ---- K-steps ----
#pragma unroll
                for (int ks = 0; ks < 12; ++ks) {
                    const bf16x8 af = *(const bf16x8*)(hsr + ks * 1024 + rdoff);
#pragma unroll
                    for (int n = 0; n < 2; ++n)
                        acc[n] = __builtin_amdgcn_mfma_f32_16x16x32_bf16(af, WR[ks][n], acc[n], 0, 0, 0);
                }
#pragma unroll
                for (int ks = 12; ks < 16; ++ks) {
                    const bf16x8 af = *(const bf16x8*)(hsr + ks * 1024 + rdoff);
#pragma unroll
                    for (int n = 0; n < 2; ++n) {
                        const bf16x8 bfr = *(const bf16x8*)(WL + (((ks - 12) * 32 + wq * 2 + n) * 64 + l) * 16);
                        acc[n] = __builtin_amdgcn_mfma_f32_16x16x32_bf16(af, bfr, acc[n], 0, 0, 0);
                    }
                }
                if (isA) {  // x @ Wih0^T extension K-step
#pragma unroll
                    for (int n = 0; n < 2; ++n)
                        acc[n] = __builtin_amdgcn_mfma_f32_16x16x32_bf16(xa, EB[n], acc[n], 0, 0, 0);
                } else {
                    acc[0] += zn0;
                    acc[1] += zn1;
                }

                // ---- epilogue ----
                if (!isA && i == NS - 1) {
                    // encoded = PRE-tanh (arctanh(tanh(s)) == s)
#pragma unroll
                    for (int n = 0; n < 2; ++n) {
                        const int col = (wq * 2 + n) * 16 + lm;
#pragma unroll
                        for (int jr = 0; jr < 4; ++jr)
                            enc[(size_t)(g * 16 + q * 4 + jr) * NH + col] = acc[n][jr];
                    }
                } else {
#pragma unroll
                    for (int n = 0; n < 2; ++n) {
                        const int col = (wq * 2 + n) * 16 + lm;
                        const int ks  = col >> 5;
                        const int cq  = (col >> 3) & 3;
                        const int bo  = (col & 7) * 2;
#pragma unroll
                        for (int jr = 0; jr < 4; ++jr) {
                            const float th = fast_tanh(acc[n][jr]);
                            const int slot = (q * 4 + jr) | (cq << 4);
                            *(__bf16*)(hsw + ks * 1024 + swzb(slot) + bo) = (__bf16)th;
                        }
                    }
                }
                __syncthreads();  // hsw complete for all waves

                if (isA) {
                    // copy new h1 (LDS swizzled) -> h1ring (global, logical-linear)
                    char* rdst = rsl + (size_t)t * 16384;
                    {
                        const int e = tid;           // 1024 threads, 1024 elems
                        const int ks = e >> 6, slot = e & 63;
                        const bf16x8 v = *(const bf16x8*)(hsw + ks * 1024 + swzb(slot));
                        *(bf16x8*)(rdst + ks * 1024 + slot * 16) = v;
                    }
                }
            }

            // ---- chunk-exit publish ----
            __syncthreads();
            if (tid == 0) {
                if (isA)
                    __hip_atomic_store(&F[g * 16], c + 1, __ATOMIC_RELEASE, __HIP_MEMORY_SCOPE_AGENT);
                else
                    __hip_atomic_store(&F[256 + g * 16], c + 1, __ATOMIC_RELEASE, __HIP_MEMORY_SCOPE_AGENT);
            }
        }
    } else {
        // ================= G role: z[c] = h1[c] @ Wih1^T + bias =================
        char* HB = lds;            // [0,32768) h1 t-slab double buffer
        char* WL = lds + 32768;

        bf16x8 WR[12][2];
#pragma unroll
        for (int ks = 0; ks < 12; ++ks)
#pragma unroll
            for (int n = 0; n < 2; ++n)
                WR[ks][n] = *(const bf16x8*)(fragG + ((size_t)(ks * 32 + wq * 2 + n) * 64 + l) * 16);
#pragma unroll
        for (int ks = 12; ks < 16; ++ks)
#pragma unroll
            for (int n = 0; n < 2; ++n) {
                const bf16x8 v = *(const bf16x8*)(fragG + ((size_t)(ks * 32 + wq * 2 + n) * 64 + l) * 16);
                *(bf16x8*)(WL + (((ks - 12) * 32 + wq * 2 + n) * 64 + l) * 16) = v;
            }
        float bv[2];
#pragma unroll
        for (int n = 0; n < 2; ++n) {
            const int col = (wq * 2 + n) * 16 + lm;
            bv[n] = ebih1[col] + ebhh1[col];
        }
        __syncthreads();

#pragma unroll 1
        for (int c = 0; c < NCH; ++c) {
            if (tid == 0) {
                while (aload(&F[g * 16]) < c + 1) __builtin_amdgcn_s_sleep(2);
                if (c >= 2)
                    while (aload(&F[256 + g * 16]) < c - 1) __builtin_amdgcn_s_sleep(2);
            }
            __syncthreads();
            __builtin_amdgcn_fence(__ATOMIC_ACQUIRE, "agent");

            const char* rsl = h1ring + (size_t)((g * 2 + (c & 1)) * CH) * 16384;
            char*       zsl = zring  + (size_t)((g * 2 + (c & 1)) * CH) * 32768;

            // stage t=0 (16 B/thread, coalesced)
            *(f32x4*)(HB + tid * 16) = *(const f32x4*)(rsl + tid * 16);
            __syncthreads();

#pragma unroll 1
            for (int t = 0; t < CH; ++t) {
                const char* bufr = HB + (t & 1) * 16384;
                char*       bufw = HB + ((t + 1) & 1) * 16384;
                f32x4 p0;
                const bool pf = (t + 1 < CH);
                if (pf) p0 = *(const f32x4*)(rsl + (size_t)(t + 1) * 16384 + tid * 16);

                f32x4 acc[2];
#pragma unroll
                for (int n = 0; n < 2; ++n)
                    acc[n] = (f32x4){bv[n], bv[n], bv[n], bv[n]};
#pragma unroll
                for (int ks = 0; ks < 12; ++ks) {
                    const bf16x8 af = *(const bf16x8*)(bufr + ks * 1024 + l * 16);
#pragma unroll
                    for (int n = 0; n < 2; ++n)
                        acc[n] = __builtin_amdgcn_mfma_f32_16x16x32_bf16(af, WR[ks][n], acc[n], 0, 0, 0);
                }
#pragma unroll
                for (int ks = 12; ks < 16; ++ks) {
                    const bf16x8 af = *(const bf16x8*)(bufr + ks * 1024 + l * 16);
#pragma unroll
                    for (int n = 0; n < 2; ++n) {
                        const bf16x8 bfr = *(const bf16x8*)(WL + (((ks - 12) * 32 + wq * 2 + n) * 64 + l) * 16);
                        acc[n] = __builtin_amdgcn_mfma_f32_16x16x32_bf16(af, bfr, acc[n], 0, 0, 0);
                    }
                }
#pragma unroll
                for (int n = 0; n < 2; ++n)
                    *(f32x4*)(zsl + (size_t)t * 32768 + ((wq * 2 + n) * 64 + l) * 16) = acc[n];

                __syncthreads();            // everyone done reading bufw's old data
                if (pf) *(f32x4*)(bufw + tid * 16) = p0;
                __syncthreads();            // staged slab visible
            }

            __syncthreads();
            if (tid == 0)
                __hip_atomic_store(&F[512 + g * 32 + c], 1, __ATOMIC_RELEASE, __HIP_MEMORY_SCOPE_AGENT);
        }
    }
}

// ---------------------------------------------------------------------------
// Batch-axis softmax stats per hidden column.
// ---------------------------------------------------------------------------
__global__ void colstats_kernel(const float* __restrict__ encoded,
                                float* __restrict__ colmax,
                                float* __restrict__ rsinv)
{
    const int h = blockIdx.x;
    const int lane = threadIdx.x;  // 64
    float v[4];
#pragma unroll
    for (int r = 0; r < 4; ++r) v[r] = encoded[(size_t)(lane + 64 * r) * NH + h];
    float mx = fmaxf(fmaxf(v[0], v[1]), fmaxf(v[2], v[3]));
#pragma unroll
    for (int s = 1; s < 64; s <<= 1) mx = fmaxf(mx, __shfl_xor(mx, s));
    float sum = 0.f;
#pragma unroll
    for (int r = 0; r < 4; ++r) sum += __expf(v[r] - mx);
#pragma unroll
    for (int s = 1; s < 64; s <<= 1) sum += __shfl_xor(sum, s);
    if (lane == 0) { colmax[h] = mx; rsinv[h] = 1.0f / sum; }
}

// ---------------------------------------------------------------------------
// Decoder: one batch element per thread; 4-dim recurrence in registers.
// ---------------------------------------------------------------------------
__global__ void decoder_kernel(
    const float* __restrict__ encoded,
    const float* __restrict__ colmax, const float* __restrict__ rsinv,
    const float* __restrict__ dWih0, const float* __restrict__ dWhh0,
    const float* __restrict__ dbih0, const float* __restrict__ dbhh0,
    const float* __restrict__ dWih1, const float* __restrict__ dWhh1,
    const float* __restrict__ dbih1, const float* __restrict__ dbhh1,
    float* __restrict__ out)
{
    const int b = blockIdx.x * 64 + threadIdx.x;

    float W0[16], Wi[16], W1[16];
#pragma unroll
    for (int e = 0; e < 16; ++e) { W0[e] = dWhh0[e]; Wi[e] = dWih1[e]; W1[e] = dWhh1[e]; }

    float c1[4], c2[4];
#pragma unroll
    for (int j = 0; j < 4; ++j) { c1[j] = dbih0[j] + dbhh0[j]; c2[j] = dbih1[j] + dbhh1[j]; }

    const float* er = encoded + (size_t)b * NH;
#pragma unroll 1
    for (int h = 0; h < NH; h += 4) {
        const float4 ev = *(const float4*)(er + h);
        const float4 cm = *(const float4*)(colmax + h);
        const float4 rs = *(const float4*)(rsinv + h);
        float p0 = __expf(ev.x - cm.x) * rs.x;
        float p1 = __expf(ev.y - cm.y) * rs.y;
        float p2 = __expf(ev.z - cm.z) * rs.z;
        float p3 = __expf(ev.w - cm.w) * rs.w;
#pragma unroll
        for (int j = 0; j < 4; ++j) {
            const float4 w = *(const float4*)(dWih0 + (size_t)j * NH + h);
            c1[j] += p0 * w.x + p1 * w.y + p2 * w.z + p3 * w.w;
        }
    }

    float h1[4] = {0.f, 0.f, 0.f, 0.f};
    float h2[4] = {0.f, 0.f, 0.f, 0.f};
    float* op = out + (size_t)b * NS * NV;

#pragma unroll 1
    for (int t = 0; t < NS; ++t) {
        float n1[4];
#pragma unroll
        for (int j = 0; j < 4; ++j)
            n1[j] = fast_tanh(c1[j] + W0[j*4+0]*h1[0] + W0[j*4+1]*h1[1]
                                    + W0[j*4+2]*h1[2] + W0[j*4+3]*h1[3]);
        float n2[4];
#pragma unroll
        for (int j = 0; j < 4; ++j)
            n2[j] = fast_tanh(c2[j] + Wi[j*4+0]*n1[0] + Wi[j*4+1]*n1[1]
                                    + Wi[j*4+2]*n1[2] + Wi[j*4+3]*n1[3]
                                    + W1[j*4+0]*h2[0] + W1[j*4+1]*h2[1]
                                    + W1[j*4+2]*h2[2] + W1[j*4+3]*h2[3]);
#pragma unroll
        for (int j = 0; j < 4; ++j) { h1[j] = n1[j]; h2[j] = n2[j]; }
        *(float4*)(op + (size_t)t * NV) = make_float4(n2[0], n2[1], n2[2], n2[3]);
    }
}

extern "C" void kernel_launch(void* const* d_in, const int* in_sizes, int n_in,
                              void* d_out, int out_size, void* d_ws, size_t ws_size,
                              hipStream_t stream)
{
    const float* x     = (const float*)d_in[0];
    const float* eWih0 = (const float*)d_in[1];
    const float* eWhh0 = (const float*)d_in[2];
    const float* ebih0 = (const float*)d_in[3];
    const float* ebhh0 = (const float*)d_in[4];
    const float* eWih1 = (const float*)d_in[5];
    const float* eWhh1 = (const float*)d_in[6];
    const float* ebih1 = (const float*)d_in[7];
    const float* ebhh1 = (const float*)d_in[8];
    const float* dWih0 = (const float*)d_in[9];
    const float* dWhh0 = (const float*)d_in[10];
    const float* dbih0 = (const float*)d_in[11];
    const float* dbhh0 = (const float*)d_in[12];
    const float* dWih1 = (const float*)d_in[13];
    const float* dWhh1 = (const float*)d_in[14];
    const float* dbih1 = (const float*)d_in[15];
    const float* dbhh1 = (const float*)d_in[16];

    char*  ws     = (char*)d_ws;
    float* enc    = (float*)(ws + ENC_OFF);
    float* colmax = (float*)(ws + CM_OFF);
    float* rsinv  = (float*)(ws + RS_OFF);

    hipFuncSetAttribute((const void*)persist_kernel,
                        hipFuncAttributeMaxDynamicSharedMemorySize, 163840);

    // zero flags
    hipMemsetAsync(d_ws, 0, 4096, stream);

    // one-shot weight fragmentation (bf16 B-frag layout)
    prep_kernel<<<96, 256, 0, stream>>>(eWhh0, eWhh1, eWih1, ws);

    // persistent pipelined encoder (16 waves/WG)
    persist_kernel<<<48, 1024, 163840, stream>>>(x, eWih0, ebih0, ebhh0,
                                                 ebih1, ebhh1, ws);

    colstats_kernel<<<NH, 64, 0, stream>>>(enc, colmax, rsinv);
    decoder_kernel<<<4, 64, 0, stream>>>(enc, colmax, rsinv,
                                         dWih0, dWhh0, dbih0, dbhh0,
                                         dWih1, dWhh1, dbih1, dbhh1,
                                         (float*)d_out);
}